// Round 2
// baseline (123.178 us; speedup 1.0000x reference)
//
#include <hip/hip_runtime.h>
#include <math.h>

// ---------------------------------------------------------------------------
// PCA local frames.  Per node: cov = sum_j outer(pos[src]-pos[dst]) over its
// 64 padded edges (contiguous block, padded slots have src==dst -> ev=0),
// then 3x3 symmetric eigendecomposition, frames = eigvecs^T (ascending
// eigenvalues), zeroed where num_neighbors <= 1.
//
// Sign-exactness strategy: replicate numpy's CPU path bit-for-bit:
//   ssyevd = SSYTD2 (lower) -> SSTEDC -> SSTEQR('I') -> SORM2R/SLARF1F.
// LAPACK-proper routines (ssteqr/slartg/slaev2/slarfg scalar parts) are
// compiled by OpenBLAS for baseline x86-64 (NO FMA)  -> contract-off C.
// BLAS kernels (ssymv/sdot/saxpy/ssyr2/sgemv_t/sger) are arch-optimized
// with -mfma -ffp-contract=fast -> emulated here with __builtin_fmaf in
// the exact OpenBLAS evaluation order (haswell/zen tails, LAPACK 3.12
// slarf1f structure).  These differ from reference Fortran only in final
// ulps — invisible for well-conditioned nodes, decisive for the few
// rank-deficient corner nodes whose degenerate subspace is rounding-
// determined.
// ---------------------------------------------------------------------------

#pragma clang fp contract(off)

#define EPS_F32    5.9604645e-8f     /* SLAMCH('E') = 2^-24            */
#define SAFMIN_F32 1.17549435e-38f   /* SLAMCH('S') = 2^-126           */

__device__ __forceinline__ float lapy2f(float x, float y) {
#pragma clang fp contract(off)
  float xa = fabsf(x), ya = fabsf(y);
  float w = fmaxf(xa, ya);
  float z = fminf(xa, ya);
  if (z == 0.0f) return w;
  float t = z / w;
  return w * sqrtf(1.0f + t * t);
}

// LAPACK >= 3.10 slartg (float32).
__device__ __forceinline__ void slartgf(float f, float g, float* c, float* s, float* r) {
#pragma clang fp contract(off)
  const float safmin = SAFMIN_F32;
  const float safmax = 8.50705917e37f;   // 1/safmin
  const float rtmin  = 1.08420217e-19f;  // sqrt(safmin)
  const float rtmax  = 6.52530446e18f;   // sqrt(safmax/2)
  if (g == 0.0f) { *c = 1.0f; *s = 0.0f; *r = f; return; }
  if (f == 0.0f) { *c = 0.0f; *s = copysignf(1.0f, g); *r = fabsf(g); return; }
  float f1 = fabsf(f), g1 = fabsf(g);
  if (f1 > rtmin && f1 < rtmax && g1 > rtmin && g1 < rtmax) {
    float d = sqrtf(f * f + g * g);
    *c = f1 / d;
    *r = copysignf(d, f);
    *s = g / (*r);
  } else {
    float u  = fminf(safmax, fmaxf(safmin, fmaxf(f1, g1)));
    float fs = f / u, gs = g / u;
    float d  = sqrtf(fs * fs + gs * gs);
    *c = fabsf(fs) / d;
    float rr = copysignf(d, f);
    *s = gs / rr;
    *r = rr * u;
  }
}

// LAPACK slaev2 (float32), verbatim transcription.
__device__ __forceinline__ void slaev2f(float a, float b, float c,
                                        float* rt1, float* rt2,
                                        float* cs1, float* sn1) {
#pragma clang fp contract(off)
  float sm  = a + c;
  float df  = a - c;
  float adf = fabsf(df);
  float tb  = b + b;
  float ab  = fabsf(tb);
  float acmx, acmn;
  if (fabsf(a) > fabsf(c)) { acmx = a; acmn = c; } else { acmx = c; acmn = a; }
  float rt;
  if (adf > ab)      { float t = ab / adf; rt = adf * sqrtf(1.0f + t * t); }
  else if (adf < ab) { float t = adf / ab; rt = ab  * sqrtf(1.0f + t * t); }
  else               { rt = ab * sqrtf(2.0f); }
  int sgn1;
  if (sm < 0.0f) {
    *rt1 = 0.5f * (sm - rt); sgn1 = -1;
    *rt2 = (acmx / *rt1) * acmn - (b / *rt1) * b;
  } else if (sm > 0.0f) {
    *rt1 = 0.5f * (sm + rt); sgn1 = 1;
    *rt2 = (acmx / *rt1) * acmn - (b / *rt1) * b;
  } else {
    *rt1 = 0.5f * rt; *rt2 = -0.5f * rt; sgn1 = 1;
  }
  int sgn2; float cs;
  if (df >= 0.0f) { cs = df + rt; sgn2 = 1; }
  else            { cs = df - rt; sgn2 = -1; }
  float acs = fabsf(cs);
  if (acs > ab) {
    float ct = -tb / cs;
    *sn1 = 1.0f / sqrtf(1.0f + ct * ct);
    *cs1 = ct * (*sn1);
  } else {
    if (ab == 0.0f) { *cs1 = 1.0f; *sn1 = 0.0f; }
    else {
      float tn = -cs / tb;
      *cs1 = 1.0f / sqrtf(1.0f + tn * tn);
      *sn1 = tn * (*cs1);
    }
  }
  if (sgn1 == sgn2) { float tn = *cs1; *cs1 = -(*sn1); *sn1 = tn; }
}

// LAPACK ssteqr('I'), specialized to n=3.  d_[3], e_[2]; z_ row-major 3x3.
// 1-based macro indexing = literal transcription.  (Pure Fortran in the
// reference binary -> no FMA anywhere here.)
__device__ void ssteqr3(float* d_, float* e_, float* z_) {
#pragma clang fp contract(off)
#define D_(i)   d_[(i)-1]
#define E_(i)   e_[(i)-1]
#define Z_(i,j) z_[((i)-1)*3 + ((j)-1)]
  const int   n      = 3;
  const float eps    = EPS_F32;
  const float eps2   = eps * eps;
  const float safmin = SAFMIN_F32;
  const float ssfmax = sqrtf(8.50705917e37f) / 3.0f;  // sqrt(1/safmin)/3
  const float ssfmin = sqrtf(safmin) / eps2;

  float work_c[2], work_s[2];
  int   l1, l, m, lsv, lend, lendsv, iscale, nmaxit, jtot;
  float anorm, p, g, r, rt1, rt2, c, s, f, b;

  for (int q = 0; q < 9; ++q) z_[q] = 0.0f;
  z_[0] = z_[4] = z_[8] = 1.0f;

  nmaxit = n * 30;
  jtot   = 0;
  l1     = 1;

L10:
  if (l1 > n) goto L160;
  if (l1 > 1) E_(l1 - 1) = 0.0f;
  if (l1 <= n - 1) {
    for (m = l1; m <= n - 1; m++) {
      float tst = fabsf(E_(m));
      if (tst == 0.0f) goto L30;
      if (tst <= (sqrtf(fabsf(D_(m))) * sqrtf(fabsf(D_(m + 1)))) * eps) {
        E_(m) = 0.0f;
        goto L30;
      }
    }
  }
  m = n;
L30:
  l = l1; lsv = l; lend = m; lendsv = lend; l1 = m + 1;
  if (lend == l) goto L10;

  // anorm = slanst('M', ...)
  anorm = 0.0f;
  for (int q = l; q <= lend; q++)     anorm = fmaxf(anorm, fabsf(D_(q)));
  for (int q = l; q <= lend - 1; q++) anorm = fmaxf(anorm, fabsf(E_(q)));
  iscale = 0;
  if (anorm == 0.0f) goto L10;
  if (anorm > ssfmax) {
    iscale = 1;
    float sc = ssfmax / anorm;
    for (int q = l; q <= lend; q++)     D_(q) *= sc;
    for (int q = l; q <= lend - 1; q++) E_(q) *= sc;
  } else if (anorm < ssfmin) {
    iscale = 2;
    float sc = ssfmin / anorm;
    for (int q = l; q <= lend; q++)     D_(q) *= sc;
    for (int q = l; q <= lend - 1; q++) E_(q) *= sc;
  }

  if (fabsf(D_(lend)) < fabsf(D_(l))) { lend = lsv; l = lendsv; }

  if (lend > l) {
    // ---------------- QL iteration ----------------
L40:
    if (l != lend) {
      for (m = l; m <= lend - 1; m++) {
        float tst = E_(m) * E_(m);
        if (tst <= (eps2 * fabsf(D_(m))) * fabsf(D_(m + 1)) + safmin) goto L60;
      }
    }
    m = lend;
L60:
    if (m < lend) E_(m) = 0.0f;
    p = D_(l);
    if (m == l) goto L80;
    if (m == l + 1) {
      slaev2f(D_(l), E_(l), D_(l + 1), &rt1, &rt2, &c, &s);
      work_c[l - 1] = c;
      work_s[l - 1] = s;
      // slasr 'R','V','B', 1 rotation on global cols (l, l+1)
      for (int row = 1; row <= n; row++) {
        float t = Z_(row, l + 1);
        Z_(row, l + 1) = c * t - s * Z_(row, l);
        Z_(row, l)     = s * t + c * Z_(row, l);
      }
      D_(l) = rt1; D_(l + 1) = rt2; E_(l) = 0.0f;
      l += 2;
      if (l <= lend) goto L40;
      goto L140;
    }
    if (jtot == nmaxit) goto L140;
    jtot++;
    g = (D_(l + 1) - p) / (2.0f * E_(l));
    r = lapy2f(g, 1.0f);
    g = D_(m) - p + (E_(l) / (g + copysignf(r, g)));
    s = 1.0f; c = 1.0f; p = 0.0f;
    for (int i = m - 1; i >= l; i--) {
      f = s * E_(i);
      b = c * E_(i);
      slartgf(g, f, &c, &s, &r);
      if (i != m - 1) E_(i + 1) = r;
      g = D_(i + 1) - p;
      r = (D_(i) - g) * s + 2.0f * c * b;
      p = s * r;
      D_(i + 1) = g + p;
      g = c * r - b;
      work_c[i - 1] = c;
      work_s[i - 1] = -s;
    }
    {
      int mm = m - l + 1;  // slasr 'R','V','B'
      for (int j = mm - 1; j >= 1; j--) {
        float cj = work_c[l + j - 2];
        float sj = work_s[l + j - 2];
        if (cj != 1.0f || sj != 0.0f) {
          int col = l + j - 1;
          for (int row = 1; row <= n; row++) {
            float t = Z_(row, col + 1);
            Z_(row, col + 1) = cj * t - sj * Z_(row, col);
            Z_(row, col)     = sj * t + cj * Z_(row, col);
          }
        }
      }
    }
    D_(l) = D_(l) - p;
    E_(l) = g;
    goto L40;
L80:
    D_(l) = p;
    l++;
    if (l <= lend) goto L40;
    goto L140;
  } else {
    // ---------------- QR iteration ----------------
L90:
    if (l != lend) {
      for (m = l; m >= lend + 1; m--) {
        float tst = E_(m - 1) * E_(m - 1);
        if (tst <= (eps2 * fabsf(D_(m))) * fabsf(D_(m - 1)) + safmin) goto L110;
      }
    }
    m = lend;
L110:
    if (m > lend) E_(m - 1) = 0.0f;
    p = D_(l);
    if (m == l) goto L130;
    if (m == l - 1) {
      slaev2f(D_(l - 1), E_(l - 1), D_(l), &rt1, &rt2, &c, &s);
      work_c[m - 1] = c;
      work_s[m - 1] = s;
      // slasr 'R','V','F', 1 rotation on global cols (l-1, l)
      for (int row = 1; row <= n; row++) {
        float t = Z_(row, l);
        Z_(row, l)     = c * t - s * Z_(row, l - 1);
        Z_(row, l - 1) = s * t + c * Z_(row, l - 1);
      }
      D_(l - 1) = rt1; D_(l) = rt2; E_(l - 1) = 0.0f;
      l -= 2;
      if (l >= lend) goto L90;
      goto L140;
    }
    if (jtot == nmaxit) goto L140;
    jtot++;
    g = (D_(l - 1) - p) / (2.0f * E_(l - 1));
    r = lapy2f(g, 1.0f);
    g = D_(m) - p + (E_(l - 1) / (g + copysignf(r, g)));
    s = 1.0f; c = 1.0f; p = 0.0f;
    for (int i = m; i <= l - 1; i++) {
      f = s * E_(i);
      b = c * E_(i);
      slartgf(g, f, &c, &s, &r);
      if (i != m) E_(i - 1) = r;
      g = D_(i) - p;
      r = (D_(i + 1) - g) * s + 2.0f * c * b;
      p = s * r;
      D_(i) = g + p;
      g = c * r - b;
      work_c[i - 1] = c;
      work_s[i - 1] = s;
    }
    {
      int mm = l - m + 1;  // slasr 'R','V','F'
      for (int j = 1; j <= mm - 1; j++) {
        float cj = work_c[m + j - 2];
        float sj = work_s[m + j - 2];
        if (cj != 1.0f || sj != 0.0f) {
          int col = m + j - 1;
          for (int row = 1; row <= n; row++) {
            float t = Z_(row, col + 1);
            Z_(row, col + 1) = cj * t - sj * Z_(row, col);
            Z_(row, col)     = sj * t + cj * Z_(row, col);
          }
        }
      }
    }
    D_(l) = D_(l) - p;
    E_(l - 1) = g;
    goto L90;
L130:
    D_(l) = p;
    l--;
    if (l >= lend) goto L90;
    goto L140;
  }

L140:
  if (iscale == 1) {
    float sc = anorm / ssfmax;
    for (int q = lsv; q <= lendsv; q++)     D_(q) *= sc;
    for (int q = lsv; q <= lendsv - 1; q++) E_(q) *= sc;
  } else if (iscale == 2) {
    float sc = anorm / ssfmin;
    for (int q = lsv; q <= lendsv; q++)     D_(q) *= sc;
    for (int q = lsv; q <= lendsv - 1; q++) E_(q) *= sc;
  }
  if (jtot < nmaxit) goto L10;
  goto L160;  // (non-convergence: impossible for 3x3 in practice)

L160:
  // ascending selection sort with column swaps (ssteqr tail, icompz>0)
  for (int ii = 2; ii <= n; ii++) {
    int i = ii - 1, kk = i;
    p = D_(i);
    for (int j = ii; j <= n; j++) {
      if (D_(j) < p) { kk = j; p = D_(j); }
    }
    if (kk != i) {
      D_(kk) = D_(i);
      D_(i)  = p;
      for (int row = 1; row <= n; row++) {
        float t = Z_(row, i);
        Z_(row, i)  = Z_(row, kk);
        Z_(row, kk) = t;
      }
    }
  }
#undef D_
#undef E_
#undef Z_
}

__global__ void __launch_bounds__(64)
pca_frames_kernel(const float* __restrict__ pos,
                  const int*   __restrict__ esrc,
                  const int*   __restrict__ nn,
                  float*       __restrict__ out,
                  int n, int k)
{
#pragma clang fp contract(off)
  int i = blockIdx.x * blockDim.x + threadIdx.x;
  if (i >= n) return;
  float* o = out + (size_t)i * 9;

  if (nn[i] <= 1) {
    #pragma unroll
    for (int j = 0; j < 9; ++j) o[j] = 0.0f;
    return;
  }

  // ---- covariance, sequential in edge order (matches np.add.at order) ----
  float px = pos[3 * i + 0], py = pos[3 * i + 1], pz = pos[3 * i + 2];
  float c00 = 0.0f, c01 = 0.0f, c02 = 0.0f, c11 = 0.0f, c12 = 0.0f, c22 = 0.0f;
  const int* ep = esrc + (size_t)i * k;
  for (int j = 0; j < k; ++j) {
    int sidx = ep[j];
    float dx = pos[3 * sidx + 0] - px;
    float dy = pos[3 * sidx + 1] - py;
    float dz = pos[3 * sidx + 2] - pz;
    c00 = c00 + dx * dx;
    c01 = c01 + dx * dy;
    c02 = c02 + dx * dz;
    c11 = c11 + dy * dy;
    c12 = c12 + dy * dz;
    c22 = c22 + dz * dz;
  }

  // ---- SSYTD2, n=3, lower (one Householder), OpenBLAS-FMA BLAS model ----
  float d_[3], e_[2], tau1, v2;
  {
    float a11 = c00, a21 = c01, a31 = c02, a22 = c11, a32 = c12, a33 = c22;
    float xnorm = fabsf(a31);          // snrm2(1,.) = |x|
    if (xnorm == 0.0f) {
      tau1 = 0.0f; v2 = 0.0f;
      d_[0] = a11; d_[1] = a22; d_[2] = a33;
      e_[0] = a21; e_[1] = a32;
    } else {
      // slarfg (Fortran, no FMA)
      float py2  = lapy2f(a21, xnorm);
      float beta = -copysignf(py2, a21);
      tau1 = (beta - a21) / beta;
      v2   = a31 * (1.0f / (a21 - beta));   // sscal: x *= rn(1/(alpha-beta))
      // ssymv lower (OpenBLAS haswell tail, FMA): w = tau * A22 * v, v=(1,v2)
      float t2 = a32 * v2;                               // temp2 = rn(a32*v2)
      float w1 = __builtin_fmaf(tau1, t2, tau1 * a22);   // y0 = fma(tau,t2, rn(tau*a22))
      float w2 = __builtin_fmaf(tau1 * v2, a33, tau1 * a32); // y1
      // sdot (OpenBLAS tail, FMA): dot = fma(v2, w2, w1)
      float dot = __builtin_fmaf(v2, w2, w1);
      // ssytd2 Fortran: alpha = rn((-0.5*tau) * dot)   (-0.5*tau exact)
      float ac = (-0.5f * tau1) * dot;
      // saxpy (FMA): w += ac * v
      w1 = w1 + ac;                          // fma(ac,1,w1) == rn(w1+ac)
      w2 = __builtin_fmaf(ac, v2, w2);
      // ssyr2 alpha=-1 (OpenBLAS syr2_k driver: per column, axpy(alpha*x[i], y)
      // THEN axpy(alpha*y[i], x), both FMA):
      float A11 = a22 - w1;                  // fma(-1,w1,a22)
      A11 = A11 - w1;                        // fma(-w1,1,A11)
      float A21 = a32 - w2;                  // fma(-1,w2,a32)
      A21 = __builtin_fmaf(-w1, v2, A21);    // true fma
      float A33 = __builtin_fmaf(-v2, w2, a33);  // true fma
      A33 = __builtin_fmaf(-w2, v2, A33);        // true fma
      d_[0] = a11;
      d_[1] = A11;
      e_[1] = A21;
      d_[2] = A33;
      e_[0] = beta;
    }
  }

  // ---- SSTEQR('I') on the tridiagonal ----
  float z_[9];
  ssteqr3(d_, e_, z_);

  // ---- SORM2R / SLARF1F (LAPACK 3.12): vecs = H1 * Z, u=(0,1,v2) ----
  // w_j = rn(z2j + rn(z3j*v2))  [gemv_t m=1 then saxpy(1,...)]
  // z2j' = fma(-tau, w_j, z2j)  [saxpy FMA]
  // z3j' = fma(v2, -rn(tau*w_j), z3j)  [ger: temp=rn(-tau*w_j), FMA]
  if (tau1 != 0.0f) {
    #pragma unroll
    for (int j = 0; j < 3; ++j) {
      float z2 = z_[3 + j], z3 = z_[6 + j];
      float w  = z2 + z3 * v2;
      float t  = tau1 * w;
      z_[3 + j] = __builtin_fmaf(-tau1, w, z2);
      z_[6 + j] = __builtin_fmaf(v2, -t, z3);
    }
  }

  // frames[j][k] = vecs[k][j]  ->  out[i*9 + j*3 + k] = z_[k*3 + j]
  o[0] = z_[0]; o[1] = z_[3]; o[2] = z_[6];
  o[3] = z_[1]; o[4] = z_[4]; o[5] = z_[7];
  o[6] = z_[2]; o[7] = z_[5]; o[8] = z_[8];
}

extern "C" void kernel_launch(void* const* d_in, const int* in_sizes, int n_in,
                              void* d_out, int out_size, void* d_ws, size_t ws_size,
                              hipStream_t stream) {
  const float* pos  = (const float*)d_in[0];
  const int*   esrc = (const int*)d_in[1];
  // d_in[2] = edge_dst: unused (layout is repeat(arange(n), k) by construction)
  const int*   nn   = (const int*)d_in[3];
  float*       out  = (float*)d_out;

  int n = in_sizes[0] / 3;
  if (n <= 0) return;
  int k = in_sizes[1] / n;

  const int block = 64;
  const int grid  = (n + block - 1) / block;
  hipLaunchKernelGGL(pca_frames_kernel, dim3(grid), dim3(block), 0, stream,
                     pos, esrc, nn, out, n, k);
}

// Round 4
// 110.669 us; speedup vs baseline: 1.1130x; 1.1130x over previous
//
#include <hip/hip_runtime.h>
#include <math.h>

// ---------------------------------------------------------------------------
// PCA local frames, single-kernel LDS-staged version.
//
// Round-3 lesson: a producer->consumer split across two kernels through d_ws
// passed direct-launch validation but diverged under graph replay (stale /
// poisoned lines reaching the consumer — CDNA4 per-XCD L2 non-coherence,
// guide G16).  So: ONE kernel, staging through LDS only.
//
// Structure per 256-thread block (owns 64 nodes):
//   Stage 1: all 256 threads gather the block's 64x64 edges cooperatively
//     (coalesced esrc reads, 16 independent gather iterations for MLP) and
//     write ev = pos[src]-pos[dst] into LDS (node stride 193 floats -> no
//     bank conflicts in either phase).
//   Stage 2: lanes 0..63 (wave 0), one node per lane: covariance summed in
//     EXACT edge order with EXACT round-2 rounding (rn products, sequential
//     rn adds), then the validated LAPACK-replica eigensolve.
//
// Sign-exactness (validated round 2): replicate numpy's CPU ssyevd path:
// SSYTD2(lower) -> SSTEQR('I') -> SLARF1F, OpenBLAS-FMA BLAS tails,
// contract-off everywhere else.  DO NOT change summation order or FMA
// placement — rank-deficient corner nodes are rounding-trajectory-determined.
// ---------------------------------------------------------------------------

#pragma clang fp contract(off)

#define EPS_F32    5.9604645e-8f     /* SLAMCH('E') = 2^-24            */
#define SAFMIN_F32 1.17549435e-38f   /* SLAMCH('S') = 2^-126           */

__device__ __forceinline__ float lapy2f(float x, float y) {
#pragma clang fp contract(off)
  float xa = fabsf(x), ya = fabsf(y);
  float w = fmaxf(xa, ya);
  float z = fminf(xa, ya);
  if (z == 0.0f) return w;
  float t = z / w;
  return w * sqrtf(1.0f + t * t);
}

// LAPACK >= 3.10 slartg (float32).
__device__ __forceinline__ void slartgf(float f, float g, float* c, float* s, float* r) {
#pragma clang fp contract(off)
  const float safmin = SAFMIN_F32;
  const float safmax = 8.50705917e37f;   // 1/safmin
  const float rtmin  = 1.08420217e-19f;  // sqrt(safmin)
  const float rtmax  = 6.52530446e18f;   // sqrt(safmax/2)
  if (g == 0.0f) { *c = 1.0f; *s = 0.0f; *r = f; return; }
  if (f == 0.0f) { *c = 0.0f; *s = copysignf(1.0f, g); *r = fabsf(g); return; }
  float f1 = fabsf(f), g1 = fabsf(g);
  if (f1 > rtmin && f1 < rtmax && g1 > rtmin && g1 < rtmax) {
    float d = sqrtf(f * f + g * g);
    *c = f1 / d;
    *r = copysignf(d, f);
    *s = g / (*r);
  } else {
    float u  = fminf(safmax, fmaxf(safmin, fmaxf(f1, g1)));
    float fs = f / u, gs = g / u;
    float d  = sqrtf(fs * fs + gs * gs);
    *c = fabsf(fs) / d;
    float rr = copysignf(d, f);
    *s = gs / rr;
    *r = rr * u;
  }
}

// LAPACK slaev2 (float32), verbatim transcription.
__device__ __forceinline__ void slaev2f(float a, float b, float c,
                                        float* rt1, float* rt2,
                                        float* cs1, float* sn1) {
#pragma clang fp contract(off)
  float sm  = a + c;
  float df  = a - c;
  float adf = fabsf(df);
  float tb  = b + b;
  float ab  = fabsf(tb);
  float acmx, acmn;
  if (fabsf(a) > fabsf(c)) { acmx = a; acmn = c; } else { acmx = c; acmn = a; }
  float rt;
  if (adf > ab)      { float t = ab / adf; rt = adf * sqrtf(1.0f + t * t); }
  else if (adf < ab) { float t = adf / ab; rt = ab  * sqrtf(1.0f + t * t); }
  else               { rt = ab * sqrtf(2.0f); }
  int sgn1;
  if (sm < 0.0f) {
    *rt1 = 0.5f * (sm - rt); sgn1 = -1;
    *rt2 = (acmx / *rt1) * acmn - (b / *rt1) * b;
  } else if (sm > 0.0f) {
    *rt1 = 0.5f * (sm + rt); sgn1 = 1;
    *rt2 = (acmx / *rt1) * acmn - (b / *rt1) * b;
  } else {
    *rt1 = 0.5f * rt; *rt2 = -0.5f * rt; sgn1 = 1;
  }
  int sgn2; float cs;
  if (df >= 0.0f) { cs = df + rt; sgn2 = 1; }
  else            { cs = df - rt; sgn2 = -1; }
  float acs = fabsf(cs);
  if (acs > ab) {
    float ct = -tb / cs;
    *sn1 = 1.0f / sqrtf(1.0f + ct * ct);
    *cs1 = ct * (*sn1);
  } else {
    if (ab == 0.0f) { *cs1 = 1.0f; *sn1 = 0.0f; }
    else {
      float tn = -cs / tb;
      *cs1 = 1.0f / sqrtf(1.0f + tn * tn);
      *sn1 = tn * (*cs1);
    }
  }
  if (sgn1 == sgn2) { float tn = *cs1; *cs1 = -(*sn1); *sn1 = tn; }
}

// LAPACK ssteqr('I'), specialized to n=3.  (No FMA: reference is pure
// Fortran compiled for baseline x86-64.)
__device__ void ssteqr3(float* d_, float* e_, float* z_) {
#pragma clang fp contract(off)
#define D_(i)   d_[(i)-1]
#define E_(i)   e_[(i)-1]
#define Z_(i,j) z_[((i)-1)*3 + ((j)-1)]
  const int   n      = 3;
  const float eps    = EPS_F32;
  const float eps2   = eps * eps;
  const float safmin = SAFMIN_F32;
  const float ssfmax = sqrtf(8.50705917e37f) / 3.0f;
  const float ssfmin = sqrtf(safmin) / eps2;

  float work_c[2], work_s[2];
  int   l1, l, m, lsv, lend, lendsv, iscale, nmaxit, jtot;
  float anorm, p, g, r, rt1, rt2, c, s, f, b;

  for (int q = 0; q < 9; ++q) z_[q] = 0.0f;
  z_[0] = z_[4] = z_[8] = 1.0f;

  nmaxit = n * 30;
  jtot   = 0;
  l1     = 1;

L10:
  if (l1 > n) goto L160;
  if (l1 > 1) E_(l1 - 1) = 0.0f;
  if (l1 <= n - 1) {
    for (m = l1; m <= n - 1; m++) {
      float tst = fabsf(E_(m));
      if (tst == 0.0f) goto L30;
      if (tst <= (sqrtf(fabsf(D_(m))) * sqrtf(fabsf(D_(m + 1)))) * eps) {
        E_(m) = 0.0f;
        goto L30;
      }
    }
  }
  m = n;
L30:
  l = l1; lsv = l; lend = m; lendsv = lend; l1 = m + 1;
  if (lend == l) goto L10;

  anorm = 0.0f;
  for (int q = l; q <= lend; q++)     anorm = fmaxf(anorm, fabsf(D_(q)));
  for (int q = l; q <= lend - 1; q++) anorm = fmaxf(anorm, fabsf(E_(q)));
  iscale = 0;
  if (anorm == 0.0f) goto L10;
  if (anorm > ssfmax) {
    iscale = 1;
    float sc = ssfmax / anorm;
    for (int q = l; q <= lend; q++)     D_(q) *= sc;
    for (int q = l; q <= lend - 1; q++) E_(q) *= sc;
  } else if (anorm < ssfmin) {
    iscale = 2;
    float sc = ssfmin / anorm;
    for (int q = l; q <= lend; q++)     D_(q) *= sc;
    for (int q = l; q <= lend - 1; q++) E_(q) *= sc;
  }

  if (fabsf(D_(lend)) < fabsf(D_(l))) { lend = lsv; l = lendsv; }

  if (lend > l) {
L40:
    if (l != lend) {
      for (m = l; m <= lend - 1; m++) {
        float tst = E_(m) * E_(m);
        if (tst <= (eps2 * fabsf(D_(m))) * fabsf(D_(m + 1)) + safmin) goto L60;
      }
    }
    m = lend;
L60:
    if (m < lend) E_(m) = 0.0f;
    p = D_(l);
    if (m == l) goto L80;
    if (m == l + 1) {
      slaev2f(D_(l), E_(l), D_(l + 1), &rt1, &rt2, &c, &s);
      work_c[l - 1] = c;
      work_s[l - 1] = s;
      for (int row = 1; row <= n; row++) {
        float t = Z_(row, l + 1);
        Z_(row, l + 1) = c * t - s * Z_(row, l);
        Z_(row, l)     = s * t + c * Z_(row, l);
      }
      D_(l) = rt1; D_(l + 1) = rt2; E_(l) = 0.0f;
      l += 2;
      if (l <= lend) goto L40;
      goto L140;
    }
    if (jtot == nmaxit) goto L140;
    jtot++;
    g = (D_(l + 1) - p) / (2.0f * E_(l));
    r = lapy2f(g, 1.0f);
    g = D_(m) - p + (E_(l) / (g + copysignf(r, g)));
    s = 1.0f; c = 1.0f; p = 0.0f;
    for (int i = m - 1; i >= l; i--) {
      f = s * E_(i);
      b = c * E_(i);
      slartgf(g, f, &c, &s, &r);
      if (i != m - 1) E_(i + 1) = r;
      g = D_(i + 1) - p;
      r = (D_(i) - g) * s + 2.0f * c * b;
      p = s * r;
      D_(i + 1) = g + p;
      g = c * r - b;
      work_c[i - 1] = c;
      work_s[i - 1] = -s;
    }
    {
      int mm = m - l + 1;  // slasr 'R','V','B'
      for (int j = mm - 1; j >= 1; j--) {
        float cj = work_c[l + j - 2];
        float sj = work_s[l + j - 2];
        if (cj != 1.0f || sj != 0.0f) {
          int col = l + j - 1;
          for (int row = 1; row <= n; row++) {
            float t = Z_(row, col + 1);
            Z_(row, col + 1) = cj * t - sj * Z_(row, col);
            Z_(row, col)     = sj * t + cj * Z_(row, col);
          }
        }
      }
    }
    D_(l) = D_(l) - p;
    E_(l) = g;
    goto L40;
L80:
    D_(l) = p;
    l++;
    if (l <= lend) goto L40;
    goto L140;
  } else {
L90:
    if (l != lend) {
      for (m = l; m >= lend + 1; m--) {
        float tst = E_(m - 1) * E_(m - 1);
        if (tst <= (eps2 * fabsf(D_(m))) * fabsf(D_(m - 1)) + safmin) goto L110;
      }
    }
    m = lend;
L110:
    if (m > lend) E_(m - 1) = 0.0f;
    p = D_(l);
    if (m == l) goto L130;
    if (m == l - 1) {
      slaev2f(D_(l - 1), E_(l - 1), D_(l), &rt1, &rt2, &c, &s);
      work_c[m - 1] = c;
      work_s[m - 1] = s;
      for (int row = 1; row <= n; row++) {
        float t = Z_(row, l);
        Z_(row, l)     = c * t - s * Z_(row, l - 1);
        Z_(row, l - 1) = s * t + c * Z_(row, l - 1);
      }
      D_(l - 1) = rt1; D_(l) = rt2; E_(l - 1) = 0.0f;
      l -= 2;
      if (l >= lend) goto L90;
      goto L140;
    }
    if (jtot == nmaxit) goto L140;
    jtot++;
    g = (D_(l - 1) - p) / (2.0f * E_(l - 1));
    r = lapy2f(g, 1.0f);
    g = D_(m) - p + (E_(l - 1) / (g + copysignf(r, g)));
    s = 1.0f; c = 1.0f; p = 0.0f;
    for (int i = m; i <= l - 1; i++) {
      f = s * E_(i);
      b = c * E_(i);
      slartgf(g, f, &c, &s, &r);
      if (i != m) E_(i - 1) = r;
      g = D_(i) - p;
      r = (D_(i + 1) - g) * s + 2.0f * c * b;
      p = s * r;
      D_(i) = g + p;
      g = c * r - b;
      work_c[i - 1] = c;
      work_s[i - 1] = s;
    }
    {
      int mm = l - m + 1;  // slasr 'R','V','F'
      for (int j = 1; j <= mm - 1; j++) {
        float cj = work_c[m + j - 2];
        float sj = work_s[m + j - 2];
        if (cj != 1.0f || sj != 0.0f) {
          int col = m + j - 1;
          for (int row = 1; row <= n; row++) {
            float t = Z_(row, col + 1);
            Z_(row, col + 1) = cj * t - sj * Z_(row, col);
            Z_(row, col)     = sj * t + cj * Z_(row, col);
          }
        }
      }
    }
    D_(l) = D_(l) - p;
    E_(l - 1) = g;
    goto L90;
L130:
    D_(l) = p;
    l--;
    if (l >= lend) goto L90;
    goto L140;
  }

L140:
  if (iscale == 1) {
    float sc = anorm / ssfmax;
    for (int q = lsv; q <= lendsv; q++)     D_(q) *= sc;
    for (int q = lsv; q <= lendsv - 1; q++) E_(q) *= sc;
  } else if (iscale == 2) {
    float sc = anorm / ssfmin;
    for (int q = lsv; q <= lendsv; q++)     D_(q) *= sc;
    for (int q = lsv; q <= lendsv - 1; q++) E_(q) *= sc;
  }
  if (jtot < nmaxit) goto L10;
  goto L160;

L160:
  for (int ii = 2; ii <= n; ii++) {
    int i = ii - 1, kk = i;
    p = D_(i);
    for (int j = ii; j <= n; j++) {
      if (D_(j) < p) { kk = j; p = D_(j); }
    }
    if (kk != i) {
      D_(kk) = D_(i);
      D_(i)  = p;
      for (int row = 1; row <= n; row++) {
        float t = Z_(row, i);
        Z_(row, i)  = Z_(row, kk);
        Z_(row, kk) = t;
      }
    }
  }
#undef D_
#undef E_
#undef Z_
}

// Shared epilogue: cov -> frames (validated bit-exact path).
__device__ __forceinline__ void eig_frames(float c00, float c01, float c02,
                                           float c11, float c12, float c22,
                                           float* __restrict__ o) {
#pragma clang fp contract(off)
  // ---- SSYTD2, n=3, lower (one Householder), OpenBLAS-FMA BLAS model ----
  float d_[3], e_[2], tau1, v2;
  {
    float a11 = c00, a21 = c01, a31 = c02, a22 = c11, a32 = c12, a33 = c22;
    float xnorm = fabsf(a31);
    if (xnorm == 0.0f) {
      tau1 = 0.0f; v2 = 0.0f;
      d_[0] = a11; d_[1] = a22; d_[2] = a33;
      e_[0] = a21; e_[1] = a32;
    } else {
      float py2  = lapy2f(a21, xnorm);
      float beta = -copysignf(py2, a21);
      tau1 = (beta - a21) / beta;
      v2   = a31 * (1.0f / (a21 - beta));
      float t2 = a32 * v2;
      float w1 = __builtin_fmaf(tau1, t2, tau1 * a22);
      float w2 = __builtin_fmaf(tau1 * v2, a33, tau1 * a32);
      float dot = __builtin_fmaf(v2, w2, w1);
      float ac = (-0.5f * tau1) * dot;
      w1 = w1 + ac;
      w2 = __builtin_fmaf(ac, v2, w2);
      float A11 = a22 - w1;
      A11 = A11 - w1;
      float A21 = a32 - w2;
      A21 = __builtin_fmaf(-w1, v2, A21);
      float A33 = __builtin_fmaf(-v2, w2, a33);
      A33 = __builtin_fmaf(-w2, v2, A33);
      d_[0] = a11;
      d_[1] = A11;
      e_[1] = A21;
      d_[2] = A33;
      e_[0] = beta;
    }
  }

  float z_[9];
  ssteqr3(d_, e_, z_);

  // SLARF1F apply
  if (tau1 != 0.0f) {
    #pragma unroll
    for (int j = 0; j < 3; ++j) {
      float z2 = z_[3 + j], z3 = z_[6 + j];
      float w  = z2 + z3 * v2;
      float t  = tau1 * w;
      z_[3 + j] = __builtin_fmaf(-tau1, w, z2);
      z_[6 + j] = __builtin_fmaf(v2, -t, z3);
    }
  }

  o[0] = z_[0]; o[1] = z_[3]; o[2] = z_[6];
  o[3] = z_[1]; o[4] = z_[4]; o[5] = z_[7];
  o[6] = z_[2]; o[7] = z_[5]; o[8] = z_[8];
}

// ---------------------------------------------------------------------------
// Tiled single kernel: 256 threads / 64 nodes per block.
//   LDS layout: sev[node*193 + slot*3 + c]  (stride 193 => conflict-free:
//   stage-1 wave writes one node row, bank = (3*lane+c)%32 spread;
//   stage-2 lane n reads row n, bank = (n + 3j)%32 spread.)
// ---------------------------------------------------------------------------
#define NODES_PER_BLOCK 64
#define NODE_STRIDE     193   /* 64*3 + 1 pad */

__global__ void __launch_bounds__(256)
pca_frames_tiled_kernel(const float* __restrict__ pos,
                        const int*   __restrict__ esrc,
                        const int*   __restrict__ nn,
                        float*       __restrict__ out,
                        int n)
{
#pragma clang fp contract(off)
  __shared__ float sev[NODES_PER_BLOCK * NODE_STRIDE];  // 49408 B

  const int tid   = threadIdx.x;
  const int block = blockIdx.x;
  const int node0 = block * NODES_PER_BLOCK;

  // ---- Stage 1: cooperative gather of this block's 64*64 edges ----
  // thread t, iter q handles block-local edge eb = q*256 + t:
  //   node n_b = eb>>6, slot j = eb&63;  global edge = block*4096 + eb.
  const int ebase = block * (NODES_PER_BLOCK * 64);
  #pragma unroll
  for (int q = 0; q < 16; ++q) {
    int eb  = q * 256 + tid;
    int n_b = eb >> 6;
    int j   = eb & 63;
    int i   = node0 + n_b;
    int s   = esrc[ebase + eb];
    // identical rounding to the validated fused kernel: rn(pos_s - pos_i)
    float dx = pos[3 * s + 0] - pos[3 * i + 0];
    float dy = pos[3 * s + 1] - pos[3 * i + 1];
    float dz = pos[3 * s + 2] - pos[3 * i + 2];
    float* row = sev + n_b * NODE_STRIDE + 3 * j;
    row[0] = dx;
    row[1] = dy;
    row[2] = dz;
  }

  __syncthreads();

  // ---- Stage 2: wave 0, one node per lane: ordered covariance + eigensolve ----
  if (tid < NODES_PER_BLOCK) {
    int i = node0 + tid;
    float* o = out + (size_t)i * 9;

    if (nn[i] <= 1) {
      #pragma unroll
      for (int j = 0; j < 9; ++j) o[j] = 0.0f;
      return;
    }

    const float* row = sev + tid * NODE_STRIDE;
    float c00 = 0.0f, c01 = 0.0f, c02 = 0.0f, c11 = 0.0f, c12 = 0.0f, c22 = 0.0f;
    // EXACT sequential edge order, EXACT rounding of the validated kernel:
    // products rn'd individually, adds sequential.
    for (int j = 0; j < 64; ++j) {
      float dx = row[3 * j + 0];
      float dy = row[3 * j + 1];
      float dz = row[3 * j + 2];
      c00 = c00 + dx * dx;
      c01 = c01 + dx * dy;
      c02 = c02 + dx * dz;
      c11 = c11 + dy * dy;
      c12 = c12 + dy * dz;
      c22 = c22 + dz * dz;
    }

    eig_frames(c00, c01, c02, c11, c12, c22, o);
  }
}

// ---------------------------------------------------------------------------
// Fallback: the validated single-kernel version (used if shape is unexpected).
// ---------------------------------------------------------------------------
__global__ void __launch_bounds__(64)
pca_frames_fused_kernel(const float* __restrict__ pos,
                        const int*   __restrict__ esrc,
                        const int*   __restrict__ nn,
                        float*       __restrict__ out,
                        int n, int k)
{
#pragma clang fp contract(off)
  int i = blockIdx.x * blockDim.x + threadIdx.x;
  if (i >= n) return;
  float* o = out + (size_t)i * 9;

  if (nn[i] <= 1) {
    #pragma unroll
    for (int j = 0; j < 9; ++j) o[j] = 0.0f;
    return;
  }

  float px = pos[3 * i + 0], py = pos[3 * i + 1], pz = pos[3 * i + 2];
  float c00 = 0.0f, c01 = 0.0f, c02 = 0.0f, c11 = 0.0f, c12 = 0.0f, c22 = 0.0f;
  const int* ep = esrc + (size_t)i * k;
  for (int j = 0; j < k; ++j) {
    int sidx = ep[j];
    float dx = pos[3 * sidx + 0] - px;
    float dy = pos[3 * sidx + 1] - py;
    float dz = pos[3 * sidx + 2] - pz;
    c00 = c00 + dx * dx;
    c01 = c01 + dx * dy;
    c02 = c02 + dx * dz;
    c11 = c11 + dy * dy;
    c12 = c12 + dy * dz;
    c22 = c22 + dz * dz;
  }

  eig_frames(c00, c01, c02, c11, c12, c22, o);
}

extern "C" void kernel_launch(void* const* d_in, const int* in_sizes, int n_in,
                              void* d_out, int out_size, void* d_ws, size_t ws_size,
                              hipStream_t stream) {
  const float* pos  = (const float*)d_in[0];
  const int*   esrc = (const int*)d_in[1];
  // d_in[2] = edge_dst: unused (layout is repeat(arange(n), k) by construction)
  const int*   nn   = (const int*)d_in[3];
  float*       out  = (float*)d_out;

  int n = in_sizes[0] / 3;
  if (n <= 0) return;
  int k = in_sizes[1] / n;

  if (k == 64 && (n % NODES_PER_BLOCK) == 0) {
    hipLaunchKernelGGL(pca_frames_tiled_kernel, dim3(n / NODES_PER_BLOCK),
                       dim3(256), 0, stream, pos, esrc, nn, out, n);
  } else {
    const int block = 64;
    hipLaunchKernelGGL(pca_frames_fused_kernel, dim3((n + block - 1) / block),
                       dim3(block), 0, stream, pos, esrc, nn, out, n, k);
  }
}

// Round 5
// 104.593 us; speedup vs baseline: 1.1777x; 1.0581x over previous
//
#include <hip/hip_runtime.h>
#include <math.h>

// ---------------------------------------------------------------------------
// PCA local frames, single-kernel LDS-staged version, round 5.
//
// Round-4 counters: VALUBusy 16.7%, occupancy 6.4% -> stage-2 eigensolve is
// latency-bound on (a) solver arrays demoted to SCRATCH (dynamic indexing,
// VGPR_Count=68 proves they're not in registers; ~200cyc/access) and (b) only
// 512 sixty-four-lane divergent waves for the whole GPU.
// This round: per-lane solver state (d[3],e[2],z[9],work[4] = 18 floats) in
// LDS, lane-stride 16 (bank set {l, l+16} per lane -> conflict-free under
// divergent indexing), and stage 2 spread over all 4 waves/block with 16
// active lanes each (2048 waves, 1/4 the divergence width).
// NO floating-point operation is added/moved/reordered: output bit-identical
// to the validated round-2/round-4 kernels.
//
// Round-3 lesson: no cross-kernel d_ws producer/consumer (graph-replay
// divergence, per-XCD L2 non-coherence).  Single kernel, LDS only.
//
// Sign-exactness (validated round 2): replicate numpy's CPU ssyevd path:
// SSYTD2(lower) -> SSTEQR('I') -> SLARF1F, OpenBLAS-FMA BLAS tails,
// contract-off everywhere else.  DO NOT change summation order or FMA
// placement — rank-deficient corner nodes are rounding-trajectory-determined.
// ---------------------------------------------------------------------------

#pragma clang fp contract(off)

#define EPS_F32    5.9604645e-8f     /* SLAMCH('E') = 2^-24            */
#define SAFMIN_F32 1.17549435e-38f   /* SLAMCH('S') = 2^-126           */

__device__ __forceinline__ float lapy2f(float x, float y) {
#pragma clang fp contract(off)
  float xa = fabsf(x), ya = fabsf(y);
  float w = fmaxf(xa, ya);
  float z = fminf(xa, ya);
  if (z == 0.0f) return w;
  float t = z / w;
  return w * sqrtf(1.0f + t * t);
}

// LAPACK >= 3.10 slartg (float32).
__device__ __forceinline__ void slartgf(float f, float g, float* c, float* s, float* r) {
#pragma clang fp contract(off)
  const float safmin = SAFMIN_F32;
  const float safmax = 8.50705917e37f;   // 1/safmin
  const float rtmin  = 1.08420217e-19f;  // sqrt(safmin)
  const float rtmax  = 6.52530446e18f;   // sqrt(safmax/2)
  if (g == 0.0f) { *c = 1.0f; *s = 0.0f; *r = f; return; }
  if (f == 0.0f) { *c = 0.0f; *s = copysignf(1.0f, g); *r = fabsf(g); return; }
  float f1 = fabsf(f), g1 = fabsf(g);
  if (f1 > rtmin && f1 < rtmax && g1 > rtmin && g1 < rtmax) {
    float d = sqrtf(f * f + g * g);
    *c = f1 / d;
    *r = copysignf(d, f);
    *s = g / (*r);
  } else {
    float u  = fminf(safmax, fmaxf(safmin, fmaxf(f1, g1)));
    float fs = f / u, gs = g / u;
    float d  = sqrtf(fs * fs + gs * gs);
    *c = fabsf(fs) / d;
    float rr = copysignf(d, f);
    *s = gs / rr;
    *r = rr * u;
  }
}

// LAPACK slaev2 (float32), verbatim transcription.
__device__ __forceinline__ void slaev2f(float a, float b, float c,
                                        float* rt1, float* rt2,
                                        float* cs1, float* sn1) {
#pragma clang fp contract(off)
  float sm  = a + c;
  float df  = a - c;
  float adf = fabsf(df);
  float tb  = b + b;
  float ab  = fabsf(tb);
  float acmx, acmn;
  if (fabsf(a) > fabsf(c)) { acmx = a; acmn = c; } else { acmx = c; acmn = a; }
  float rt;
  if (adf > ab)      { float t = ab / adf; rt = adf * sqrtf(1.0f + t * t); }
  else if (adf < ab) { float t = adf / ab; rt = ab  * sqrtf(1.0f + t * t); }
  else               { rt = ab * sqrtf(2.0f); }
  int sgn1;
  if (sm < 0.0f) {
    *rt1 = 0.5f * (sm - rt); sgn1 = -1;
    *rt2 = (acmx / *rt1) * acmn - (b / *rt1) * b;
  } else if (sm > 0.0f) {
    *rt1 = 0.5f * (sm + rt); sgn1 = 1;
    *rt2 = (acmx / *rt1) * acmn - (b / *rt1) * b;
  } else {
    *rt1 = 0.5f * rt; *rt2 = -0.5f * rt; sgn1 = 1;
  }
  int sgn2; float cs;
  if (df >= 0.0f) { cs = df + rt; sgn2 = 1; }
  else            { cs = df - rt; sgn2 = -1; }
  float acs = fabsf(cs);
  if (acs > ab) {
    float ct = -tb / cs;
    *sn1 = 1.0f / sqrtf(1.0f + ct * ct);
    *cs1 = ct * (*sn1);
  } else {
    if (ab == 0.0f) { *cs1 = 1.0f; *sn1 = 0.0f; }
    else {
      float tn = -cs / tb;
      *cs1 = 1.0f / sqrtf(1.0f + tn * tn);
      *sn1 = tn * (*cs1);
    }
  }
  if (sgn1 == sgn2) { float tn = *cs1; *cs1 = -(*sn1); *sn1 = tn; }
}

// ---------------------------------------------------------------------------
// LAPACK ssteqr('I') n=3, state in LDS at lane-stride STR:
//   S[(0..2)*STR]=d, S[(3..4)*STR]=e, S[(5..13)*STR]=z (row-major),
//   S[(14..15)*STR]=work_c, S[(16..17)*STR]=work_s.
// Literal transcription — arithmetic identical to the validated version.
// ---------------------------------------------------------------------------
template <int STR>
__device__ void ssteqr3(float* S) {
#pragma clang fp contract(off)
#define D_(i)   S[((i)-1)*STR]
#define E_(i)   S[(3+(i)-1)*STR]
#define Z_(i,j) S[(5+((i)-1)*3+((j)-1))*STR]
#define WC_(q)  S[(14+(q))*STR]
#define WS_(q)  S[(16+(q))*STR]
  const int   n      = 3;
  const float eps    = EPS_F32;
  const float eps2   = eps * eps;
  const float safmin = SAFMIN_F32;
  const float ssfmax = sqrtf(8.50705917e37f) / 3.0f;
  const float ssfmin = sqrtf(safmin) / eps2;

  int   l1, l, m, lsv, lend, lendsv, iscale, nmaxit, jtot;
  float anorm, p, g, r, rt1, rt2, c, s, f, b;

  for (int q = 0; q < 9; ++q) S[(5 + q) * STR] = 0.0f;
  Z_(1, 1) = 1.0f; Z_(2, 2) = 1.0f; Z_(3, 3) = 1.0f;

  nmaxit = n * 30;
  jtot   = 0;
  l1     = 1;

L10:
  if (l1 > n) goto L160;
  if (l1 > 1) E_(l1 - 1) = 0.0f;
  if (l1 <= n - 1) {
    for (m = l1; m <= n - 1; m++) {
      float tst = fabsf(E_(m));
      if (tst == 0.0f) goto L30;
      if (tst <= (sqrtf(fabsf(D_(m))) * sqrtf(fabsf(D_(m + 1)))) * eps) {
        E_(m) = 0.0f;
        goto L30;
      }
    }
  }
  m = n;
L30:
  l = l1; lsv = l; lend = m; lendsv = lend; l1 = m + 1;
  if (lend == l) goto L10;

  anorm = 0.0f;
  for (int q = l; q <= lend; q++)     anorm = fmaxf(anorm, fabsf(D_(q)));
  for (int q = l; q <= lend - 1; q++) anorm = fmaxf(anorm, fabsf(E_(q)));
  iscale = 0;
  if (anorm == 0.0f) goto L10;
  if (anorm > ssfmax) {
    iscale = 1;
    float sc = ssfmax / anorm;
    for (int q = l; q <= lend; q++)     D_(q) *= sc;
    for (int q = l; q <= lend - 1; q++) E_(q) *= sc;
  } else if (anorm < ssfmin) {
    iscale = 2;
    float sc = ssfmin / anorm;
    for (int q = l; q <= lend; q++)     D_(q) *= sc;
    for (int q = l; q <= lend - 1; q++) E_(q) *= sc;
  }

  if (fabsf(D_(lend)) < fabsf(D_(l))) { lend = lsv; l = lendsv; }

  if (lend > l) {
L40:
    if (l != lend) {
      for (m = l; m <= lend - 1; m++) {
        float tst = E_(m) * E_(m);
        if (tst <= (eps2 * fabsf(D_(m))) * fabsf(D_(m + 1)) + safmin) goto L60;
      }
    }
    m = lend;
L60:
    if (m < lend) E_(m) = 0.0f;
    p = D_(l);
    if (m == l) goto L80;
    if (m == l + 1) {
      slaev2f(D_(l), E_(l), D_(l + 1), &rt1, &rt2, &c, &s);
      WC_(l - 1) = c;
      WS_(l - 1) = s;
      for (int row = 1; row <= n; row++) {
        float t = Z_(row, l + 1);
        Z_(row, l + 1) = c * t - s * Z_(row, l);
        Z_(row, l)     = s * t + c * Z_(row, l);
      }
      D_(l) = rt1; D_(l + 1) = rt2; E_(l) = 0.0f;
      l += 2;
      if (l <= lend) goto L40;
      goto L140;
    }
    if (jtot == nmaxit) goto L140;
    jtot++;
    g = (D_(l + 1) - p) / (2.0f * E_(l));
    r = lapy2f(g, 1.0f);
    g = D_(m) - p + (E_(l) / (g + copysignf(r, g)));
    s = 1.0f; c = 1.0f; p = 0.0f;
    for (int i = m - 1; i >= l; i--) {
      f = s * E_(i);
      b = c * E_(i);
      slartgf(g, f, &c, &s, &r);
      if (i != m - 1) E_(i + 1) = r;
      g = D_(i + 1) - p;
      r = (D_(i) - g) * s + 2.0f * c * b;
      p = s * r;
      D_(i + 1) = g + p;
      g = c * r - b;
      WC_(i - 1) = c;
      WS_(i - 1) = -s;
    }
    {
      int mm = m - l + 1;  // slasr 'R','V','B'
      for (int j = mm - 1; j >= 1; j--) {
        float cj = WC_(l + j - 2);
        float sj = WS_(l + j - 2);
        if (cj != 1.0f || sj != 0.0f) {
          int col = l + j - 1;
          for (int row = 1; row <= n; row++) {
            float t = Z_(row, col + 1);
            Z_(row, col + 1) = cj * t - sj * Z_(row, col);
            Z_(row, col)     = sj * t + cj * Z_(row, col);
          }
        }
      }
    }
    D_(l) = D_(l) - p;
    E_(l) = g;
    goto L40;
L80:
    D_(l) = p;
    l++;
    if (l <= lend) goto L40;
    goto L140;
  } else {
L90:
    if (l != lend) {
      for (m = l; m >= lend + 1; m--) {
        float tst = E_(m - 1) * E_(m - 1);
        if (tst <= (eps2 * fabsf(D_(m))) * fabsf(D_(m - 1)) + safmin) goto L110;
      }
    }
    m = lend;
L110:
    if (m > lend) E_(m - 1) = 0.0f;
    p = D_(l);
    if (m == l) goto L130;
    if (m == l - 1) {
      slaev2f(D_(l - 1), E_(l - 1), D_(l), &rt1, &rt2, &c, &s);
      WC_(m - 1) = c;
      WS_(m - 1) = s;
      for (int row = 1; row <= n; row++) {
        float t = Z_(row, l);
        Z_(row, l)     = c * t - s * Z_(row, l - 1);
        Z_(row, l - 1) = s * t + c * Z_(row, l - 1);
      }
      D_(l - 1) = rt1; D_(l) = rt2; E_(l - 1) = 0.0f;
      l -= 2;
      if (l >= lend) goto L90;
      goto L140;
    }
    if (jtot == nmaxit) goto L140;
    jtot++;
    g = (D_(l - 1) - p) / (2.0f * E_(l - 1));
    r = lapy2f(g, 1.0f);
    g = D_(m) - p + (E_(l - 1) / (g + copysignf(r, g)));
    s = 1.0f; c = 1.0f; p = 0.0f;
    for (int i = m; i <= l - 1; i++) {
      f = s * E_(i);
      b = c * E_(i);
      slartgf(g, f, &c, &s, &r);
      if (i != m) E_(i - 1) = r;
      g = D_(i) - p;
      r = (D_(i + 1) - g) * s + 2.0f * c * b;
      p = s * r;
      D_(i) = g + p;
      g = c * r - b;
      WC_(i - 1) = c;
      WS_(i - 1) = s;
    }
    {
      int mm = l - m + 1;  // slasr 'R','V','F'
      for (int j = 1; j <= mm - 1; j++) {
        float cj = WC_(m + j - 2);
        float sj = WS_(m + j - 2);
        if (cj != 1.0f || sj != 0.0f) {
          int col = m + j - 1;
          for (int row = 1; row <= n; row++) {
            float t = Z_(row, col + 1);
            Z_(row, col + 1) = cj * t - sj * Z_(row, col);
            Z_(row, col)     = sj * t + cj * Z_(row, col);
          }
        }
      }
    }
    D_(l) = D_(l) - p;
    E_(l - 1) = g;
    goto L90;
L130:
    D_(l) = p;
    l--;
    if (l >= lend) goto L90;
    goto L140;
  }

L140:
  if (iscale == 1) {
    float sc = anorm / ssfmax;
    for (int q = lsv; q <= lendsv; q++)     D_(q) *= sc;
    for (int q = lsv; q <= lendsv - 1; q++) E_(q) *= sc;
  } else if (iscale == 2) {
    float sc = anorm / ssfmin;
    for (int q = lsv; q <= lendsv; q++)     D_(q) *= sc;
    for (int q = lsv; q <= lendsv - 1; q++) E_(q) *= sc;
  }
  if (jtot < nmaxit) goto L10;
  goto L160;

L160:
  for (int ii = 2; ii <= n; ii++) {
    int i = ii - 1, kk = i;
    p = D_(i);
    for (int j = ii; j <= n; j++) {
      if (D_(j) < p) { kk = j; p = D_(j); }
    }
    if (kk != i) {
      D_(kk) = D_(i);
      D_(i)  = p;
      for (int row = 1; row <= n; row++) {
        float t = Z_(row, i);
        Z_(row, i)  = Z_(row, kk);
        Z_(row, kk) = t;
      }
    }
  }
#undef D_
#undef E_
#undef Z_
#undef WC_
#undef WS_
}

// Shared epilogue: cov -> frames.  S = per-lane LDS state base, stride STR.
template <int STR>
__device__ __forceinline__ void eig_frames(float c00, float c01, float c02,
                                           float c11, float c12, float c22,
                                           float* __restrict__ o, float* S) {
#pragma clang fp contract(off)
#define SZ(idx) S[(5 + (idx)) * STR]
  // ---- SSYTD2, n=3, lower (one Householder), OpenBLAS-FMA BLAS model ----
  float tau1, v2;
  {
    float a11 = c00, a21 = c01, a31 = c02, a22 = c11, a32 = c12, a33 = c22;
    float xnorm = fabsf(a31);
    if (xnorm == 0.0f) {
      tau1 = 0.0f; v2 = 0.0f;
      S[0 * STR] = a11; S[1 * STR] = a22; S[2 * STR] = a33;
      S[3 * STR] = a21; S[4 * STR] = a32;
    } else {
      float py2  = lapy2f(a21, xnorm);
      float beta = -copysignf(py2, a21);
      tau1 = (beta - a21) / beta;
      v2   = a31 * (1.0f / (a21 - beta));
      float t2 = a32 * v2;
      float w1 = __builtin_fmaf(tau1, t2, tau1 * a22);
      float w2 = __builtin_fmaf(tau1 * v2, a33, tau1 * a32);
      float dot = __builtin_fmaf(v2, w2, w1);
      float ac = (-0.5f * tau1) * dot;
      w1 = w1 + ac;
      w2 = __builtin_fmaf(ac, v2, w2);
      float A11 = a22 - w1;
      A11 = A11 - w1;
      float A21 = a32 - w2;
      A21 = __builtin_fmaf(-w1, v2, A21);
      float A33 = __builtin_fmaf(-v2, w2, a33);
      A33 = __builtin_fmaf(-w2, v2, A33);
      S[0 * STR] = a11;
      S[1 * STR] = A11;
      S[4 * STR] = A21;
      S[2 * STR] = A33;
      S[3 * STR] = beta;
    }
  }

  ssteqr3<STR>(S);

  // SLARF1F apply (identical FP sequence to validated kernel)
  if (tau1 != 0.0f) {
    #pragma unroll
    for (int j = 0; j < 3; ++j) {
      float z2 = SZ(3 + j), z3 = SZ(6 + j);
      float w  = z2 + z3 * v2;
      float t  = tau1 * w;
      SZ(3 + j) = __builtin_fmaf(-tau1, w, z2);
      SZ(6 + j) = __builtin_fmaf(v2, -t, z3);
    }
  }

  o[0] = SZ(0); o[1] = SZ(3); o[2] = SZ(6);
  o[3] = SZ(1); o[4] = SZ(4); o[5] = SZ(7);
  o[6] = SZ(2); o[7] = SZ(5); o[8] = SZ(8);
#undef SZ
}

// ---------------------------------------------------------------------------
// Tiled single kernel: 256 threads / 64 nodes per block.
//   sev[node*193 + slot*3 + c] : conflict-free both phases.
//   sstate: 4 waves x 16 lanes x 18 floats, lane-stride 16 -> lane l only
//   touches banks {l, l+16}: conflict-free even with divergent indices.
//   Stage 2: wave w solves nodes [16w, 16w+16) on lanes 0..15.
// ---------------------------------------------------------------------------
#define NODES_PER_BLOCK 64
#define NODE_STRIDE     193   /* 64*3 + 1 pad */
#define SOLVER_LANES    16

__global__ void __launch_bounds__(256)
pca_frames_tiled_kernel(const float* __restrict__ pos,
                        const int*   __restrict__ esrc,
                        const int*   __restrict__ nn,
                        float*       __restrict__ out,
                        int n)
{
#pragma clang fp contract(off)
  __shared__ float sev[NODES_PER_BLOCK * NODE_STRIDE];          // 49408 B
  __shared__ float sstate[4 * 18 * SOLVER_LANES];               //  4608 B

  const int tid   = threadIdx.x;
  const int node0 = blockIdx.x * NODES_PER_BLOCK;

  // ---- Stage 1: cooperative gather of this block's 64*64 edges ----
  const int ebase = blockIdx.x * (NODES_PER_BLOCK * 64);
  #pragma unroll
  for (int q = 0; q < 16; ++q) {
    int eb  = q * 256 + tid;
    int n_b = eb >> 6;          // wave-uniform
    int j   = eb & 63;
    int i   = node0 + n_b;
    int s   = esrc[ebase + eb];
    float dx = pos[3 * s + 0] - pos[3 * i + 0];
    float dy = pos[3 * s + 1] - pos[3 * i + 1];
    float dz = pos[3 * s + 2] - pos[3 * i + 2];
    float* row = sev + n_b * NODE_STRIDE + 3 * j;
    row[0] = dx;
    row[1] = dy;
    row[2] = dz;
  }

  __syncthreads();

  // ---- Stage 2: 4 waves x 16 lanes, one node per lane ----
  const int w = tid >> 6;
  const int l = tid & 63;
  if (l < SOLVER_LANES) {
    int nb = w * SOLVER_LANES + l;   // block-local node 0..63
    int i  = node0 + nb;
    float* o = out + (size_t)i * 9;

    if (nn[i] <= 1) {
      #pragma unroll
      for (int j = 0; j < 9; ++j) o[j] = 0.0f;
      return;
    }

    const float* row = sev + nb * NODE_STRIDE;
    float c00 = 0.0f, c01 = 0.0f, c02 = 0.0f, c11 = 0.0f, c12 = 0.0f, c22 = 0.0f;
    // EXACT sequential edge order, EXACT rounding (validated).
    for (int j = 0; j < 64; ++j) {
      float dx = row[3 * j + 0];
      float dy = row[3 * j + 1];
      float dz = row[3 * j + 2];
      c00 = c00 + dx * dx;
      c01 = c01 + dx * dy;
      c02 = c02 + dx * dz;
      c11 = c11 + dy * dy;
      c12 = c12 + dy * dz;
      c22 = c22 + dz * dz;
    }

    float* S = sstate + w * (18 * SOLVER_LANES) + l;
    eig_frames<SOLVER_LANES>(c00, c01, c02, c11, c12, c22, o, S);
  }
}

// ---------------------------------------------------------------------------
// Fallback (unexpected shapes): validated fused structure, state in LDS.
// ---------------------------------------------------------------------------
__global__ void __launch_bounds__(64)
pca_frames_fused_kernel(const float* __restrict__ pos,
                        const int*   __restrict__ esrc,
                        const int*   __restrict__ nn,
                        float*       __restrict__ out,
                        int n, int k)
{
#pragma clang fp contract(off)
  __shared__ float fstate[64 * 18];
  int i = blockIdx.x * blockDim.x + threadIdx.x;
  if (i >= n) return;
  float* o = out + (size_t)i * 9;

  if (nn[i] <= 1) {
    #pragma unroll
    for (int j = 0; j < 9; ++j) o[j] = 0.0f;
    return;
  }

  float px = pos[3 * i + 0], py = pos[3 * i + 1], pz = pos[3 * i + 2];
  float c00 = 0.0f, c01 = 0.0f, c02 = 0.0f, c11 = 0.0f, c12 = 0.0f, c22 = 0.0f;
  const int* ep = esrc + (size_t)i * k;
  for (int j = 0; j < k; ++j) {
    int sidx = ep[j];
    float dx = pos[3 * sidx + 0] - px;
    float dy = pos[3 * sidx + 1] - py;
    float dz = pos[3 * sidx + 2] - pz;
    c00 = c00 + dx * dx;
    c01 = c01 + dx * dy;
    c02 = c02 + dx * dz;
    c11 = c11 + dy * dy;
    c12 = c12 + dy * dz;
    c22 = c22 + dz * dz;
  }

  float* S = fstate + threadIdx.x;   // stride 64: banks {t%32} only, 2-way
  eig_frames<64>(c00, c01, c02, c11, c12, c22, o, S);
}

extern "C" void kernel_launch(void* const* d_in, const int* in_sizes, int n_in,
                              void* d_out, int out_size, void* d_ws, size_t ws_size,
                              hipStream_t stream) {
  const float* pos  = (const float*)d_in[0];
  const int*   esrc = (const int*)d_in[1];
  // d_in[2] = edge_dst: unused (layout is repeat(arange(n), k) by construction)
  const int*   nn   = (const int*)d_in[3];
  float*       out  = (float*)d_out;

  int n = in_sizes[0] / 3;
  if (n <= 0) return;
  int k = in_sizes[1] / n;

  if (k == 64 && (n % NODES_PER_BLOCK) == 0) {
    hipLaunchKernelGGL(pca_frames_tiled_kernel, dim3(n / NODES_PER_BLOCK),
                       dim3(256), 0, stream, pos, esrc, nn, out, n);
  } else {
    const int block = 64;
    hipLaunchKernelGGL(pca_frames_fused_kernel, dim3((n + block - 1) / block),
                       dim3(block), 0, stream, pos, esrc, nn, out, n, k);
  }
}